// Round 8
// baseline (417.462 us; speedup 1.0000x reference)
//
#include <hip/hip_runtime.h>

// MHA forward: B=2, S=2048, D=1024, H=16, HD=64. Inputs f32, mask int32,
// OUTPUT f32. Intermediates bf16 in ws.
//
// Round 7: barrier-free attention.
//  - QKV GEMM writes V TRANSPOSED (B,H,HD,S) so the PV B-fragment is
//    k-contiguous in global memory (no LDS transpose, no staging barrier).
//  - attention: Q/K/V^T fragments loaded directly from global (L1/L2-hot),
//    NO __syncthreads in the kernel, LDS = wave-private P transform only
//    (9 KB/block). Latency hiding via occupancy/TLP, which round 6 proved
//    is the operative mechanism (LDS 28->54 KB dropped occ 19->12%).
//  - fixed-offset softmax kept (logits bounded; clamp 30).

#define BB 2
#define SS 2048
#define DD 1024
#define HH 16
#define HDD 64
#define NEG_BIG (-1.0e30f)

typedef __attribute__((ext_vector_type(8))) short short8;
typedef __attribute__((ext_vector_type(4))) float floatx4;

__device__ __forceinline__ ushort f2bf(float f) {  // RNE
    unsigned u = __float_as_uint(f);
    u += 0x7fffu + ((u >> 16) & 1u);
    return (ushort)(u >> 16);
}
__device__ __forceinline__ unsigned pk2(float a, float b) {
    return ((unsigned)f2bf(b) << 16) | (unsigned)f2bf(a);
}
__device__ __forceinline__ void storeT(float* p, float v) { *p = v; }
__device__ __forceinline__ void storeT(ushort* p, float v) { *p = f2bf(v); }

__device__ __forceinline__ void ld16_bf(const float* p, uint4* r) {
    const float4 f0 = ((const float4*)p)[0];
    const float4 f1 = ((const float4*)p)[1];
    const float4 f2 = ((const float4*)p)[2];
    const float4 f3 = ((const float4*)p)[3];
    r[0].x = pk2(f0.x, f0.y); r[0].y = pk2(f0.z, f0.w);
    r[0].z = pk2(f1.x, f1.y); r[0].w = pk2(f1.z, f1.w);
    r[1].x = pk2(f2.x, f2.y); r[1].y = pk2(f2.z, f2.w);
    r[1].z = pk2(f3.x, f3.y); r[1].w = pk2(f3.z, f3.w);
}
__device__ __forceinline__ void ld16_bf(const ushort* p, uint4* r) {
    r[0] = ((const uint4*)p)[0];
    r[1] = ((const uint4*)p)[1];
}

// ---------------- GEMM ----------------
// QKV=1: z selects W/bias/out; z=0,1 (Q,K) -> (B,H,S,HD); z=2 (V) ->
// TRANSPOSED (B,H,HD,S). QKV=0: f32 row-major out.
template <int QKV, typename TA, typename TO>
__global__ __launch_bounds__(256) void gemm_mfma(
    const TA* __restrict__ A,
    const float* __restrict__ W0, const float* __restrict__ W1,
    const float* __restrict__ W2,
    const float* __restrict__ B0, const float* __restrict__ B1,
    const float* __restrict__ B2,
    TO* __restrict__ O0, TO* __restrict__ O1, TO* __restrict__ O2)
{
    __shared__ ushort As[128 * 40];
    __shared__ ushort Bs[128 * 40];
    __shared__ float bias_s[128];

    const float* W;
    const float* bias;
    TO* out;
    int z = 0;
    if (QKV) {
        z = blockIdx.z;
        W    = z == 0 ? W0 : (z == 1 ? W1 : W2);
        bias = z == 0 ? B0 : (z == 1 ? B1 : B2);
        out  = z == 0 ? O0 : (z == 1 ? O1 : O2);
    } else { W = W0; bias = B0; out = O0; }

    const int tid = threadIdx.x;
    const int bm = blockIdx.x * 128, bn = blockIdx.y * 128;
    const int wave = tid >> 6, lane = tid & 63, quad = lane >> 4, lm = lane & 15;
    const int wm = wave >> 1, wn = wave & 1;
    const int sr = tid >> 1, sc = (tid & 1) * 16;

    if (tid < 128) bias_s[tid] = bias[bn + tid];

    const TA* arow = A + (size_t)(bm + sr) * DD + sc;
    const float* wrow = W + (size_t)(bn + sr) * DD + sc;

    uint4 ra[2], rw[2];
    ld16_bf(arow, ra);
    ld16_bf(wrow, rw);

    const floatx4 zz = {0.f, 0.f, 0.f, 0.f};
    floatx4 acc[4][4];
#pragma unroll
    for (int i = 0; i < 4; ++i)
#pragma unroll
        for (int j = 0; j < 4; ++j) acc[i][j] = zz;

    for (int k0 = 0; k0 < DD; k0 += 32) {
        __syncthreads();
        *(uint4*)&As[sr * 40 + sc] = ra[0];
        *(uint4*)&As[sr * 40 + sc + 8] = ra[1];
        *(uint4*)&Bs[sr * 40 + sc] = rw[0];
        *(uint4*)&Bs[sr * 40 + sc + 8] = rw[1];
        __syncthreads();
        if (k0 + 32 < DD) {
            ld16_bf(arow + k0 + 32, ra);
            ld16_bf(wrow + k0 + 32, rw);
        }
        short8 af[4], bf[4];
#pragma unroll
        for (int i = 0; i < 4; ++i)
            af[i] = *(const short8*)&As[(wm * 64 + i * 16 + lm) * 40 + quad * 8];
#pragma unroll
        for (int j = 0; j < 4; ++j)
            bf[j] = *(const short8*)&Bs[(wn * 64 + j * 16 + lm) * 40 + quad * 8];
#pragma unroll
        for (int i = 0; i < 4; ++i)
#pragma unroll
            for (int j = 0; j < 4; ++j)
                acc[i][j] = __builtin_amdgcn_mfma_f32_16x16x32_bf16(
                    af[i], bf[j], acc[i][j], 0, 0, 0);
    }

#pragma unroll
    for (int i = 0; i < 4; ++i) {
#pragma unroll
        for (int j = 0; j < 4; ++j) {
            const int nl = wn * 64 + j * 16 + lm;
            const int n = bn + nl;
            const float bb = bias_s[nl];
#pragma unroll
            for (int r = 0; r < 4; ++r) {
                const int m = bm + wm * 64 + i * 16 + quad * 4 + r;
                const float v = acc[i][j][r] + bb;
                size_t oidx;
                if (QKV) {
                    const int b = m >> 11, s = m & 2047, h = n >> 6, hd = n & 63;
                    if (z == 2)  // V transposed: (B,H,HD,S)
                        oidx = (((size_t)(b * HH + h) * HDD) + hd) * SS + s;
                    else
                        oidx = (((size_t)(b * HH + h) * SS) + s) * HDD + hd;
                } else {
                    oidx = (size_t)m * DD + n;
                }
                storeT(out + oidx, v);
            }
        }
    }
}

// ---------------- Attention: barrier-free, all fragments from global -------
// Q,K: (B*H,S,HD) bf16. Vt: (B*H,HD,S) bf16. Out (B,S,D) bf16.
__global__ __launch_bounds__(256) void attn_mfma(
    const ushort* __restrict__ Q, const ushort* __restrict__ K,
    const ushort* __restrict__ Vt, const int* __restrict__ am,
    ushort* __restrict__ O)
{
    __shared__ ushort Ps[4][16 * 72];  // wave-private P transform

    const int tid = threadIdx.x;
    const int wq = tid >> 6, lane = tid & 63, quad = lane >> 4, lm = lane & 15;
    const int qt = (int)(gridDim.x - 1 - blockIdx.x);  // big blocks first
    const int bh = blockIdx.y, b = bh >> 4, h = bh & 15;
    const size_t base = (size_t)bh * SS * HDD;   // Q,K layout
    const size_t tbase = (size_t)bh * HDD * SS;  // V^T layout
    const int* amrow = am + b * SS;

    // Q fragments (this wave's 16 q rows)
    const ushort* qp = Q + base + (size_t)(qt * 64 + wq * 16 + lm) * HDD + quad * 8;
    const short8 qf0 = *(const short8*)qp;
    const short8 qf1 = *(const short8*)(qp + 32);

    int amq4[4];
#pragma unroll
    for (int r = 0; r < 4; ++r)
        amq4[r] = amrow[qt * 64 + wq * 16 + quad * 4 + r];

    const floatx4 zz = {0.f, 0.f, 0.f, 0.f};
    floatx4 o_acc[4];
#pragma unroll
    for (int n2 = 0; n2 < 4; ++n2) o_acc[n2] = zz;
    float l_r[4] = {0.f, 0.f, 0.f, 0.f};

    for (int kt = 0; kt <= qt; ++kt) {
        // ---- V^T fragments: issue loads first (consumed last) ----
        short8 vf[4][2];
#pragma unroll
        for (int n2 = 0; n2 < 4; ++n2) {
            const ushort* vp = Vt + tbase + (size_t)(n2 * 16 + lm) * SS
                               + kt * 64 + quad * 8;
            vf[n2][0] = *(const short8*)vp;
            vf[n2][1] = *(const short8*)(vp + 32);
        }

        int amk4[4];
#pragma unroll
        for (int nt = 0; nt < 4; ++nt)
            amk4[nt] = amrow[kt * 64 + nt * 16 + lm];

        // ---- S = Q K^T (K fragments straight from global) ----
        floatx4 s_acc[4];
#pragma unroll
        for (int nt = 0; nt < 4; ++nt) {
            const ushort* kp = K + base
                               + (size_t)(kt * 64 + nt * 16 + lm) * HDD + quad * 8;
            const short8 kf0 = *(const short8*)kp;
            const short8 kf1 = *(const short8*)(kp + 32);
            floatx4 zv = zz;
            zv = __builtin_amdgcn_mfma_f32_16x16x32_bf16(qf0, kf0, zv, 0, 0, 0);
            zv = __builtin_amdgcn_mfma_f32_16x16x32_bf16(qf1, kf1, zv, 0, 0, 0);
            s_acc[nt] = zv;
        }

        // ---- fixed-offset softmax ----
        const bool offdiag = (kt < qt);
        float p[4][4];
#pragma unroll
        for (int nt = 0; nt < 4; ++nt) {
            const int tl = nt * 16 + lm;
#pragma unroll
            for (int r = 0; r < 4; ++r) {
                const int ql = wq * 16 + quad * 4 + r;
                float sv = s_acc[nt][r] * 0.125f;
                const bool ok = amk4[nt] && amq4[r] && (offdiag || tl <= ql);
                sv = ok ? sv : NEG_BIG;
                const float e = __expf(fminf(sv, 30.f));
                p[nt][r] = e;
                l_r[r] += e;
            }
        }

        // ---- P: C-layout -> A-layout via wave-private LDS (no barrier) ----
#pragma unroll
        for (int nt = 0; nt < 4; ++nt)
#pragma unroll
            for (int r = 0; r < 4; ++r)
                Ps[wq][(quad * 4 + r) * 72 + nt * 16 + lm] = f2bf(p[nt][r]);

        const short8 af0 = *(const short8*)&Ps[wq][lm * 72 + quad * 8];
        const short8 af1 = *(const short8*)&Ps[wq][lm * 72 + 32 + quad * 8];

        // ---- O += P V ----
#pragma unroll
        for (int n2 = 0; n2 < 4; ++n2) {
            o_acc[n2] = __builtin_amdgcn_mfma_f32_16x16x32_bf16(af0, vf[n2][0], o_acc[n2], 0, 0, 0);
            o_acc[n2] = __builtin_amdgcn_mfma_f32_16x16x32_bf16(af1, vf[n2][1], o_acc[n2], 0, 0, 0);
        }
    }

    // ---- end-of-kernel l reduction across the 16 t-lanes ----
    float inv[4];
#pragma unroll
    for (int r = 0; r < 4; ++r) {
        float l = l_r[r];
        l += __shfl_xor(l, 1);
        l += __shfl_xor(l, 2);
        l += __shfl_xor(l, 4);
        l += __shfl_xor(l, 8);
        inv[r] = l > 0.f ? 1.f / l : 0.f;
    }
#pragma unroll
    for (int n2 = 0; n2 < 4; ++n2)
#pragma unroll
        for (int r = 0; r < 4; ++r) {
            const int s = qt * 64 + wq * 16 + quad * 4 + r;
            O[((size_t)(b * SS + s)) * DD + h * HDD + n2 * 16 + lm] =
                f2bf(o_acc[n2][r] * inv[r]);
        }
}

extern "C" void kernel_launch(void* const* d_in, const int* in_sizes, int n_in,
                              void* d_out, int out_size, void* d_ws, size_t ws_size,
                              hipStream_t stream) {
    const float* x  = (const float*)d_in[0];
    const int*   am = (const int*)d_in[1];
    const float* Wq = (const float*)d_in[2];
    const float* bq = (const float*)d_in[3];
    const float* Wk = (const float*)d_in[4];
    const float* bk = (const float*)d_in[5];
    const float* Wv = (const float*)d_in[6];
    const float* bv = (const float*)d_in[7];
    const float* Wp = (const float*)d_in[8];
    const float* bp = (const float*)d_in[9];
    float* out = (float*)d_out;

    const size_t elems = (size_t)BB * HH * SS * HDD;  // 4M
    ushort* q_ws = (ushort*)d_ws;
    ushort* k_ws = q_ws + elems;
    ushort* v_ws = k_ws + elems;  // V^T (B,H,HD,S)
    ushort* a_ws = v_ws + elems;  // (B,S,D) bf16

    gemm_mfma<1, float, ushort><<<dim3(32, 8, 3), 256, 0, stream>>>(
        x, Wq, Wk, Wv, bq, bk, bv, q_ws, k_ws, v_ws);

    attn_mfma<<<dim3(SS / 64, BB * HH), 256, 0, stream>>>(q_ws, k_ws, v_ws, am, a_ws);

    gemm_mfma<0, ushort, float><<<dim3(32, 8, 1), 256, 0, stream>>>(
        a_ws, Wp, Wp, Wp, bp, bp, bp, out, out, out);
}

// Round 9
// 251.884 us; speedup vs baseline: 1.6574x; 1.6574x over previous
//
#include <hip/hip_runtime.h>

// MHA forward: B=2, S=2048, D=1024, H=16, HD=64. Inputs f32, mask int32,
// OUTPUT f32. Intermediates bf16 in ws (32 MB). d_out (16 MB) doubles as
// scratch for bf16-converted x/Wq/Wk/Wv until proj overwrites it (Wp stays
// f32 -> no read/write race on d_out during proj).
//
// Round 8:
//  cvt_all    : x,Wq,Wk,Wv f32->bf16 into d_out scratch (14 MB)
//  gemm_mfma  : m97-style 128x128x32, global_load_lds(16B) DMA staging,
//               unpadded LDS (bank-uniform for b128 frag reads).
//               QKV=1: z=0,1 -> (B,H,S,HD); z=2 (V) -> transposed (B,H,HD,S)
//  attn_mfma  : R6-style block-LDS staging (ranked best: 142 < 157 < 237 us),
//               V^T staged vectorized (no LDS transpose), fixed-offset
//               softmax, 32 q-rows/wave (128/block) to double MFMA per tile.

#define BB 2
#define SS 2048
#define DD 1024
#define HH 16
#define HDD 64
#define NEG_BIG (-1.0e30f)

typedef __attribute__((ext_vector_type(8))) short short8;
typedef __attribute__((ext_vector_type(4))) float floatx4;
typedef unsigned int u32;
#define AS_GLOBAL __attribute__((address_space(1)))
#define AS_LDS    __attribute__((address_space(3)))

__device__ __forceinline__ ushort f2bf(float f) {  // RNE
    unsigned u = __float_as_uint(f);
    u += 0x7fffu + ((u >> 16) & 1u);
    return (ushort)(u >> 16);
}
__device__ __forceinline__ unsigned pk2(float a, float b) {
    return ((unsigned)f2bf(b) << 16) | (unsigned)f2bf(a);
}
__device__ __forceinline__ void storeT(float* p, float v) { *p = v; }
__device__ __forceinline__ void storeT(ushort* p, float v) { *p = f2bf(v); }

// async 16B global -> LDS (dest = wave-uniform base + lane*16; our lane
// pointers are constructed to satisfy exactly that).
__device__ __forceinline__ void dma16(void* lds, const void* g) {
    __builtin_amdgcn_global_load_lds((const AS_GLOBAL u32*)g, (AS_LDS u32*)lds,
                                     16, 0, 0);
}

// ---------------- f32 -> bf16 conversion (x, Wq, Wk, Wv) ----------------
// dst flat ushort regions: [0,4M) x, [4M,5M) Wq, [5M,6M) Wk, [6M,7M) Wv.
__global__ __launch_bounds__(256) void cvt_all(
    const float* __restrict__ x, const float* __restrict__ wq,
    const float* __restrict__ wk, const float* __restrict__ wv,
    ushort* __restrict__ dst)
{
    const size_t g = (size_t)blockIdx.x * 256 + threadIdx.x;  // 8-elem groups
    const size_t flat = g * 8;
    const float* s;
    size_t off;
    if (flat < (size_t)4194304)      { s = x;  off = flat; }
    else if (flat < (size_t)5242880) { s = wq; off = flat - 4194304; }
    else if (flat < (size_t)6291456) { s = wk; off = flat - 5242880; }
    else                             { s = wv; off = flat - 6291456; }
    const float4 a = ((const float4*)(s + off))[0];
    const float4 b = ((const float4*)(s + off))[1];
    uint4 u;
    u.x = pk2(a.x, a.y); u.y = pk2(a.z, a.w);
    u.z = pk2(b.x, b.y); u.w = pk2(b.z, b.w);
    *(uint4*)(dst + flat) = u;
}

// ---------------- GEMM: m97-style, DMA-staged bf16 A; W bf16(DMA)/f32 ------
template <int QKV, typename TW, typename TO>
__global__ __launch_bounds__(256) void gemm_mfma(
    const ushort* __restrict__ A,
    const TW* __restrict__ W0, const TW* __restrict__ W1,
    const TW* __restrict__ W2,
    const float* __restrict__ B0, const float* __restrict__ B1,
    const float* __restrict__ B2,
    TO* __restrict__ O0, TO* __restrict__ O1, TO* __restrict__ O2)
{
    __shared__ ushort As[128 * 32];  // unpadded: row*64B, DMA lane order
    __shared__ ushort Bs[128 * 32];
    __shared__ float bias_s[128];

    const TW* W;
    const float* bias;
    TO* out;
    int z = 0;
    if (QKV) {
        z = blockIdx.z;
        W    = z == 0 ? W0 : (z == 1 ? W1 : W2);
        bias = z == 0 ? B0 : (z == 1 ? B1 : B2);
        out  = z == 0 ? O0 : (z == 1 ? O1 : O2);
    } else { W = W0; bias = B0; out = O0; }

    const int tid = threadIdx.x;
    const int bm = blockIdx.x * 128, bn = blockIdx.y * 128;
    const int wave = tid >> 6, lane = tid & 63, quad = lane >> 4, lm = lane & 15;
    const int wm = wave >> 1, wn = wave & 1;
    const int r0 = tid >> 2, c0 = (tid & 3) * 8;  // staging coords (elems)

    if (tid < 128) bias_s[tid] = bias[bn + tid];

    const floatx4 zz = {0.f, 0.f, 0.f, 0.f};
    floatx4 acc[4][4];
#pragma unroll
    for (int i = 0; i < 4; ++i)
#pragma unroll
        for (int j = 0; j < 4; ++j) acc[i][j] = zz;

    for (int k0 = 0; k0 < DD; k0 += 32) {
        __syncthreads();  // previous tile's frag reads complete
        dma16(&As[r0 * 32 + c0], A + (size_t)(bm + r0) * DD + k0 + c0);
        dma16(&As[(64 + r0) * 32 + c0], A + (size_t)(bm + 64 + r0) * DD + k0 + c0);
        if constexpr (sizeof(TW) == 2) {
            dma16(&Bs[r0 * 32 + c0],
                  (const ushort*)W + (size_t)(bn + r0) * DD + k0 + c0);
            dma16(&Bs[(64 + r0) * 32 + c0],
                  (const ushort*)W + (size_t)(bn + 64 + r0) * DD + k0 + c0);
        } else {
#pragma unroll
            for (int hh = 0; hh < 2; ++hh) {
                const float* wr = (const float*)W
                    + (size_t)(bn + hh * 64 + r0) * DD + k0 + c0;
                const float4 a = ((const float4*)wr)[0];
                const float4 b = ((const float4*)wr)[1];
                uint4 u;
                u.x = pk2(a.x, a.y); u.y = pk2(a.z, a.w);
                u.z = pk2(b.x, b.y); u.w = pk2(b.z, b.w);
                *(uint4*)&Bs[(hh * 64 + r0) * 32 + c0] = u;
            }
        }
        __syncthreads();  // drains vmcnt (DMA) + lgkm -> tile visible

        short8 af[4], bf[4];
#pragma unroll
        for (int i = 0; i < 4; ++i)
            af[i] = *(const short8*)&As[(wm * 64 + i * 16 + lm) * 32 + quad * 8];
#pragma unroll
        for (int j = 0; j < 4; ++j)
            bf[j] = *(const short8*)&Bs[(wn * 64 + j * 16 + lm) * 32 + quad * 8];
#pragma unroll
        for (int i = 0; i < 4; ++i)
#pragma unroll
            for (int j = 0; j < 4; ++j)
                acc[i][j] = __builtin_amdgcn_mfma_f32_16x16x32_bf16(
                    af[i], bf[j], acc[i][j], 0, 0, 0);
    }

#pragma unroll
    for (int i = 0; i < 4; ++i) {
#pragma unroll
        for (int j = 0; j < 4; ++j) {
            const int nl = wn * 64 + j * 16 + lm;
            const int n = bn + nl;
            const float bb = bias_s[nl];
#pragma unroll
            for (int r = 0; r < 4; ++r) {
                const int m = bm + wm * 64 + i * 16 + quad * 4 + r;
                const float v = acc[i][j][r] + bb;
                size_t oidx;
                if (QKV) {
                    const int b = m >> 11, s = m & 2047, h = n >> 6, hd = n & 63;
                    if (z == 2)  // V transposed: (B,H,HD,S)
                        oidx = (((size_t)(b * HH + h) * HDD) + hd) * SS + s;
                    else
                        oidx = (((size_t)(b * HH + h) * SS) + s) * HDD + hd;
                } else {
                    oidx = (size_t)m * DD + n;
                }
                storeT(out + oidx, v);
            }
        }
    }
}

// ---------------- Attention: block-LDS staging, 128 q-rows/block ----------
// Q,K: (B*H,S,HD) bf16. Vt: (B*H,HD,S) bf16. Out (B,S,D) bf16.
__global__ __launch_bounds__(256) void attn_mfma(
    const ushort* __restrict__ Q, const ushort* __restrict__ K,
    const ushort* __restrict__ Vt, const int* __restrict__ am,
    ushort* __restrict__ O)
{
    __shared__ ushort Ks[64 * 72];       // K tile [t][hd]
    __shared__ ushort Vts[64 * 72];      // V^T tile [hd][t]
    __shared__ ushort Ps[4][32 * 72];    // wave-private P (32 q-rows)

    const int tid = threadIdx.x;
    const int wq = tid >> 6, lane = tid & 63, quad = lane >> 4, lm = lane & 15;
    const int qt = (int)(gridDim.x - 1 - blockIdx.x);  // big blocks first
    const int bh = blockIdx.y, b = bh >> 4, h = bh & 15;
    const size_t base = (size_t)bh * SS * HDD;   // Q,K
    const size_t tbase = (size_t)bh * HDD * SS;  // V^T
    const int* amrow = am + b * SS;
    const int q0 = qt * 128 + wq * 32;  // this wave's first q row

    // Q fragments: two 16-row subtiles
    short8 qf[2][2];
#pragma unroll
    for (int sub = 0; sub < 2; ++sub) {
        const ushort* qp = Q + base + (size_t)(q0 + sub * 16 + lm) * HDD + quad * 8;
        qf[sub][0] = *(const short8*)qp;
        qf[sub][1] = *(const short8*)(qp + 32);
    }
    int amq[2][4];
#pragma unroll
    for (int sub = 0; sub < 2; ++sub)
#pragma unroll
        for (int r = 0; r < 4; ++r)
            amq[sub][r] = amrow[q0 + sub * 16 + quad * 4 + r];

    const floatx4 zz = {0.f, 0.f, 0.f, 0.f};
    floatx4 o_acc[2][4];
#pragma unroll
    for (int sub = 0; sub < 2; ++sub)
#pragma unroll
        for (int n2 = 0; n2 < 4; ++n2) o_acc[sub][n2] = zz;
    float l_r[2][4] = {};

    const int sr = tid >> 2, sc = (tid & 3) * 16;  // staging coords
    const int ktmax = 2 * qt + 1;                  // causal: last tile w/ diag

    for (int kt = 0; kt <= ktmax; ++kt) {
        __syncthreads();  // previous tile fully consumed
        {   // stage K [t][hd]
            const ushort* kp = K + base + (size_t)(kt * 64 + sr) * HDD + sc;
            const uint4 u0 = ((const uint4*)kp)[0], u1 = ((const uint4*)kp)[1];
            *(uint4*)&Ks[sr * 72 + sc] = u0;
            *(uint4*)&Ks[sr * 72 + sc + 8] = u1;
        }
        {   // stage V^T [hd][t] (vectorized: rows already hd-major)
            const ushort* vp = Vt + tbase + (size_t)sr * SS + kt * 64 + sc;
            const uint4 u0 = ((const uint4*)vp)[0], u1 = ((const uint4*)vp)[1];
            *(uint4*)&Vts[sr * 72 + sc] = u0;
            *(uint4*)&Vts[sr * 72 + sc + 8] = u1;
        }
        __syncthreads();

        int amk4[4];
#pragma unroll
        for (int nt = 0; nt < 4; ++nt) amk4[nt] = amrow[kt * 64 + nt * 16 + lm];

        // ---- S = Q K^T, fixed-offset softmax, P write (per nt, both subs) --
#pragma unroll
        for (int nt = 0; nt < 4; ++nt) {
            const short8 kf0 = *(const short8*)&Ks[(nt * 16 + lm) * 72 + quad * 8];
            const short8 kf1 = *(const short8*)&Ks[(nt * 16 + lm) * 72 + 32 + quad * 8];
            const int tg = kt * 64 + nt * 16 + lm;
#pragma unroll
            for (int sub = 0; sub < 2; ++sub) {
                floatx4 s = zz;
                s = __builtin_amdgcn_mfma_f32_16x16x32_bf16(qf[sub][0], kf0, s, 0, 0, 0);
                s = __builtin_amdgcn_mfma_f32_16x16x32_bf16(qf[sub][1], kf1, s, 0, 0, 0);
#pragma unroll
                for (int r = 0; r < 4; ++r) {
                    const int qg = q0 + sub * 16 + quad * 4 + r;
                    float sv = s[r] * 0.125f;
                    const bool ok = amk4[nt] && amq[sub][r] && (tg <= qg);
                    sv = ok ? sv : NEG_BIG;
                    const float e = __expf(fminf(sv, 30.f));
                    l_r[sub][r] += e;
                    Ps[wq][(sub * 16 + quad * 4 + r) * 72 + nt * 16 + lm] = f2bf(e);
                }
            }
        }

        // ---- A-frags from P, O += P V ----
        short8 af[2][2];
#pragma unroll
        for (int sub = 0; sub < 2; ++sub) {
            af[sub][0] = *(const short8*)&Ps[wq][(sub * 16 + lm) * 72 + quad * 8];
            af[sub][1] = *(const short8*)&Ps[wq][(sub * 16 + lm) * 72 + 32 + quad * 8];
        }
#pragma unroll
        for (int n2 = 0; n2 < 4; ++n2) {
            const short8 vf0 = *(const short8*)&Vts[(n2 * 16 + lm) * 72 + quad * 8];
            const short8 vf1 = *(const short8*)&Vts[(n2 * 16 + lm) * 72 + 32 + quad * 8];
#pragma unroll
            for (int sub = 0; sub < 2; ++sub) {
                o_acc[sub][n2] = __builtin_amdgcn_mfma_f32_16x16x32_bf16(
                    af[sub][0], vf0, o_acc[sub][n2], 0, 0, 0);
                o_acc[sub][n2] = __builtin_amdgcn_mfma_f32_16x16x32_bf16(
                    af[sub][1], vf1, o_acc[sub][n2], 0, 0, 0);
            }
        }
    }

    // ---- end-of-kernel l reduction (within quad's 16 lm-lanes) ----
#pragma unroll
    for (int sub = 0; sub < 2; ++sub) {
        float inv[4];
#pragma unroll
        for (int r = 0; r < 4; ++r) {
            float l = l_r[sub][r];
            l += __shfl_xor(l, 1);
            l += __shfl_xor(l, 2);
            l += __shfl_xor(l, 4);
            l += __shfl_xor(l, 8);
            inv[r] = l > 0.f ? 1.f / l : 0.f;
        }
#pragma unroll
        for (int n2 = 0; n2 < 4; ++n2)
#pragma unroll
            for (int r = 0; r < 4; ++r) {
                const int s = q0 + sub * 16 + quad * 4 + r;
                O[((size_t)(b * SS + s)) * DD + h * HDD + n2 * 16 + lm] =
                    f2bf(o_acc[sub][n2][r] * inv[r]);
            }
    }
}

extern "C" void kernel_launch(void* const* d_in, const int* in_sizes, int n_in,
                              void* d_out, int out_size, void* d_ws, size_t ws_size,
                              hipStream_t stream) {
    const float* x  = (const float*)d_in[0];
    const int*   am = (const int*)d_in[1];
    const float* Wq = (const float*)d_in[2];
    const float* bq = (const float*)d_in[3];
    const float* Wk = (const float*)d_in[4];
    const float* bk = (const float*)d_in[5];
    const float* Wv = (const float*)d_in[6];
    const float* bv = (const float*)d_in[7];
    const float* Wp = (const float*)d_in[8];
    const float* bp = (const float*)d_in[9];
    float* out = (float*)d_out;

    const size_t elems = (size_t)BB * HH * SS * HDD;  // 4M
    ushort* q_ws = (ushort*)d_ws;
    ushort* k_ws = q_ws + elems;
    ushort* v_ws = k_ws + elems;  // V^T (B,H,HD,S)
    ushort* a_ws = v_ws + elems;  // (B,S,D) bf16

    // d_out scratch: bf16 x (4M elems) + Wq/Wk/Wv (1M each)
    ushort* xb  = (ushort*)d_out;
    ushort* wqb = xb + 4194304;
    ushort* wkb = wqb + 1048576;
    ushort* wvb = wkb + 1048576;

    cvt_all<<<3584, 256, 0, stream>>>(x, Wq, Wk, Wv, xb);

    gemm_mfma<1, ushort, ushort><<<dim3(32, 8, 3), 256, 0, stream>>>(
        xb, wqb, wkb, wvb, bq, bk, bv, q_ws, k_ws, v_ws);

    attn_mfma<<<dim3(SS / 128, BB * HH), 256, 0, stream>>>(q_ws, k_ws, v_ws, am, a_ws);

    gemm_mfma<0, float, float><<<dim3(32, 8, 1), 256, 0, stream>>>(
        a_ws, Wp, Wp, Wp, bp, bp, bp, out, out, out);
}

// Round 10
// 251.253 us; speedup vs baseline: 1.6615x; 1.0025x over previous
//
#include <hip/hip_runtime.h>

// MHA forward: B=2, S=2048, D=1024, H=16, HD=64. Inputs f32, mask int32,
// OUTPUT f32. Intermediates bf16.
//
// Round 9:
//  - Operand-swap trick: mfma(bf, af) computes C^T so each lane's 4 C/D regs
//    are 4 CONSECUTIVE n-columns -> epilogues pack into 8B/16B stores
//    (was 64 scattered 2B stores). Fragment reads unchanged.
//    Q/K GEMM + proj: swapped. V GEMM: unswapped (s-contiguous V^T out).
//    Attention QK^T and PV: swapped (packs P LDS writes + O stores; l becomes
//    one scalar/lane, reduced once at kernel end via shfl_xor 16/32).
//  - Split-K x2 attention (fixed-offset softmax sums combine linearly):
//    grid (16,32,2)=1024 blocks = 4 blocks/CU (LDS cap). Unnormalized bf16
//    O-partials -> d_out scratch (16 MB, dead); l0/l1 f32 -> a_ws slot;
//    combine kernel normalizes into q_ws (dead after attn); proj reads q_ws.

#define BB 2
#define SS 2048
#define DD 1024
#define HH 16
#define HDD 64
#define NEG_BIG (-1.0e30f)

typedef __attribute__((ext_vector_type(8))) short short8;
typedef __attribute__((ext_vector_type(4))) float floatx4;
typedef unsigned int u32;
#define AS_GLOBAL __attribute__((address_space(1)))
#define AS_LDS    __attribute__((address_space(3)))

__device__ __forceinline__ ushort f2bf(float f) {  // RNE
    unsigned u = __float_as_uint(f);
    u += 0x7fffu + ((u >> 16) & 1u);
    return (ushort)(u >> 16);
}
__device__ __forceinline__ unsigned pk2(float a, float b) {
    return ((unsigned)f2bf(b) << 16) | (unsigned)f2bf(a);
}
__device__ __forceinline__ void unpack8(const uint4 u, float* d) {
    d[0] = __uint_as_float(u.x << 16);
    d[1] = __uint_as_float(u.x & 0xffff0000u);
    d[2] = __uint_as_float(u.y << 16);
    d[3] = __uint_as_float(u.y & 0xffff0000u);
    d[4] = __uint_as_float(u.z << 16);
    d[5] = __uint_as_float(u.z & 0xffff0000u);
    d[6] = __uint_as_float(u.w << 16);
    d[7] = __uint_as_float(u.w & 0xffff0000u);
}
__device__ __forceinline__ void dma16(void* lds, const void* g) {
    __builtin_amdgcn_global_load_lds((const AS_GLOBAL u32*)g, (AS_LDS u32*)lds,
                                     16, 0, 0);
}

// ---------------- f32 -> bf16 conversion (x, Wq, Wk, Wv) ----------------
__global__ __launch_bounds__(256) void cvt_all(
    const float* __restrict__ x, const float* __restrict__ wq,
    const float* __restrict__ wk, const float* __restrict__ wv,
    ushort* __restrict__ dst)
{
    const size_t flat = ((size_t)blockIdx.x * 256 + threadIdx.x) * 8;
    const float* s;
    size_t off;
    if (flat < (size_t)4194304)      { s = x;  off = flat; }
    else if (flat < (size_t)5242880) { s = wq; off = flat - 4194304; }
    else if (flat < (size_t)6291456) { s = wk; off = flat - 5242880; }
    else                             { s = wv; off = flat - 6291456; }
    const float4 a = ((const float4*)(s + off))[0];
    const float4 b = ((const float4*)(s + off))[1];
    uint4 u;
    u.x = pk2(a.x, a.y); u.y = pk2(a.z, a.w);
    u.z = pk2(b.x, b.y); u.w = pk2(b.z, b.w);
    *(uint4*)(dst + flat) = u;
}

// ---------------- GEMM ----------------
// MODE 0: proj, f32 out (B,S,D), swapped (n-contiguous regs, float4 stores)
// MODE 1: Q/K, bf16 out (B,H,S,HD), swapped (ushort4), blockIdx.z picks Q/K
// MODE 2: V,  bf16 out (B,H,HD,S), unswapped (4 consecutive s, ushort4)
template <int MODE, typename TW, typename TO>
__global__ __launch_bounds__(256) void gemm_mfma(
    const ushort* __restrict__ A,
    const TW* __restrict__ W0, const TW* __restrict__ W1,
    const float* __restrict__ B0, const float* __restrict__ B1,
    TO* __restrict__ O0, TO* __restrict__ O1)
{
    __shared__ ushort As[128 * 32];
    __shared__ ushort Bs[128 * 32];
    __shared__ float bias_s[128];

    const TW* W = W0;
    const float* bias = B0;
    TO* out = O0;
    if (MODE == 1 && blockIdx.z == 1) { W = W1; bias = B1; out = O1; }

    const int tid = threadIdx.x;
    const int bm = blockIdx.x * 128, bn = blockIdx.y * 128;
    const int wave = tid >> 6, lane = tid & 63, quad = lane >> 4, lm = lane & 15;
    const int wm = wave >> 1, wn = wave & 1;
    const int r0 = tid >> 2, c0 = (tid & 3) * 8;

    if (tid < 128) bias_s[tid] = bias[bn + tid];

    const floatx4 zz = {0.f, 0.f, 0.f, 0.f};
    floatx4 acc[4][4];
#pragma unroll
    for (int i = 0; i < 4; ++i)
#pragma unroll
        for (int j = 0; j < 4; ++j) acc[i][j] = zz;

    for (int k0 = 0; k0 < DD; k0 += 32) {
        __syncthreads();
        dma16(&As[r0 * 32 + c0], A + (size_t)(bm + r0) * DD + k0 + c0);
        dma16(&As[(64 + r0) * 32 + c0], A + (size_t)(bm + 64 + r0) * DD + k0 + c0);
        if constexpr (sizeof(TW) == 2) {
            dma16(&Bs[r0 * 32 + c0],
                  (const ushort*)W + (size_t)(bn + r0) * DD + k0 + c0);
            dma16(&Bs[(64 + r0) * 32 + c0],
                  (const ushort*)W + (size_t)(bn + 64 + r0) * DD + k0 + c0);
        } else {
#pragma unroll
            for (int hh = 0; hh < 2; ++hh) {
                const float* wr = (const float*)W
                    + (size_t)(bn + hh * 64 + r0) * DD + k0 + c0;
                const float4 a = ((const float4*)wr)[0];
                const float4 b = ((const float4*)wr)[1];
                uint4 u;
                u.x = pk2(a.x, a.y); u.y = pk2(a.z, a.w);
                u.z = pk2(b.x, b.y); u.w = pk2(b.z, b.w);
                *(uint4*)&Bs[(hh * 64 + r0) * 32 + c0] = u;
            }
        }
        __syncthreads();

        short8 af[4], bf[4];
#pragma unroll
        for (int i = 0; i < 4; ++i)
            af[i] = *(const short8*)&As[(wm * 64 + i * 16 + lm) * 32 + quad * 8];
#pragma unroll
        for (int j = 0; j < 4; ++j)
            bf[j] = *(const short8*)&Bs[(wn * 64 + j * 16 + lm) * 32 + quad * 8];
#pragma unroll
        for (int i = 0; i < 4; ++i)
#pragma unroll
            for (int j = 0; j < 4; ++j) {
                if (MODE == 2)
                    acc[i][j] = __builtin_amdgcn_mfma_f32_16x16x32_bf16(
                        af[i], bf[j], acc[i][j], 0, 0, 0);
                else  // swapped: regs = consecutive n
                    acc[i][j] = __builtin_amdgcn_mfma_f32_16x16x32_bf16(
                        bf[j], af[i], acc[i][j], 0, 0, 0);
            }
    }

#pragma unroll
    for (int i = 0; i < 4; ++i) {
#pragma unroll
        for (int j = 0; j < 4; ++j) {
            if (MODE == 2) {  // unswapped: regs = 4 consecutive m (=s)
                const int n = bn + wn * 64 + j * 16 + lm;
                const int m0 = bm + wm * 64 + i * 16 + quad * 4;
                const int b = m0 >> 11, s0 = m0 & 2047;
                const float bb = bias_s[n - bn];
                ushort4 v;
                v.x = f2bf(acc[i][j][0] + bb);
                v.y = f2bf(acc[i][j][1] + bb);
                v.z = f2bf(acc[i][j][2] + bb);
                v.w = f2bf(acc[i][j][3] + bb);
                *(ushort4*)((ushort*)out + ((size_t)(b * DD + n)) * SS + s0) = v;
            } else {
                const int nl = wn * 64 + j * 16 + quad * 4;
                const int n = bn + nl;
                const int m = bm + wm * 64 + i * 16 + lm;
                if (MODE == 1) {
                    const int b = m >> 11, s = m & 2047, h = n >> 6, hd = n & 63;
                    ushort4 v;
                    v.x = f2bf(acc[i][j][0] + bias_s[nl + 0]);
                    v.y = f2bf(acc[i][j][1] + bias_s[nl + 1]);
                    v.z = f2bf(acc[i][j][2] + bias_s[nl + 2]);
                    v.w = f2bf(acc[i][j][3] + bias_s[nl + 3]);
                    *(ushort4*)((ushort*)out
                        + (((size_t)(b * HH + h) * SS) + s) * HDD + hd) = v;
                } else {  // MODE 0: f32 row-major
                    float4 v;
                    v.x = acc[i][j][0] + bias_s[nl + 0];
                    v.y = acc[i][j][1] + bias_s[nl + 1];
                    v.z = acc[i][j][2] + bias_s[nl + 2];
                    v.w = acc[i][j][3] + bias_s[nl + 3];
                    *(float4*)((float*)out + (size_t)m * DD + n) = v;
                }
            }
        }
    }
}

// ---------------- Attention: swapped MFMA, split-K x2 ----------------
// Q,K: (B*H,S,HD) bf16. Vt: (B*H,HD,S) bf16.
// Opart: 2 x (B,S,D) bf16 unnormalized. lbuf: 2 x (B*H*S) f32.
__global__ __launch_bounds__(256) void attn_mfma(
    const ushort* __restrict__ Q, const ushort* __restrict__ K,
    const ushort* __restrict__ Vt, const int* __restrict__ am,
    ushort* __restrict__ Opart, float* __restrict__ lbuf)
{
    __shared__ ushort Ks[64 * 72];
    __shared__ ushort Vts[64 * 72];
    __shared__ ushort Ps[4][32 * 72];
    __shared__ int amk_s[64];

    const int tid = threadIdx.x;
    const int wq = tid >> 6, lane = tid & 63, quad = lane >> 4, lm = lane & 15;
    const int qt = (int)(gridDim.x - 1 - blockIdx.x);  // big blocks first
    const int bh = blockIdx.y, b = bh >> 4, h = bh & 15;
    const int split = blockIdx.z;
    const size_t base = (size_t)bh * SS * HDD;
    const size_t tbase = (size_t)bh * HDD * SS;
    const int* amrow = am + b * SS;
    const int q0 = qt * 128 + wq * 32;

    short8 qf[2][2];
#pragma unroll
    for (int sub = 0; sub < 2; ++sub) {
        const ushort* qp = Q + base + (size_t)(q0 + sub * 16 + lm) * HDD + quad * 8;
        qf[sub][0] = *(const short8*)qp;
        qf[sub][1] = *(const short8*)(qp + 32);
    }
    int amq[2];
#pragma unroll
    for (int sub = 0; sub < 2; ++sub) amq[sub] = amrow[q0 + sub * 16 + lm];

    const floatx4 zz = {0.f, 0.f, 0.f, 0.f};
    floatx4 o_acc[2][4];
#pragma unroll
    for (int sub = 0; sub < 2; ++sub)
#pragma unroll
        for (int n2 = 0; n2 < 4; ++n2) o_acc[sub][n2] = zz;
    float l_lane[2] = {0.f, 0.f};

    const int sr = tid >> 2, sc = (tid & 3) * 16;
    const int ktmax = 2 * qt + 1;

    for (int kt = split; kt <= ktmax; kt += 2) {
        __syncthreads();
        {   // stage K [t][hd]
            const ushort* kp = K + base + (size_t)(kt * 64 + sr) * HDD + sc;
            const uint4 u0 = ((const uint4*)kp)[0], u1 = ((const uint4*)kp)[1];
            *(uint4*)&Ks[sr * 72 + sc] = u0;
            *(uint4*)&Ks[sr * 72 + sc + 8] = u1;
        }
        {   // stage V^T [hd][t]
            const ushort* vp = Vt + tbase + (size_t)sr * SS + kt * 64 + sc;
            const uint4 u0 = ((const uint4*)vp)[0], u1 = ((const uint4*)vp)[1];
            *(uint4*)&Vts[sr * 72 + sc] = u0;
            *(uint4*)&Vts[sr * 72 + sc + 8] = u1;
        }
        if (tid < 64) amk_s[tid] = amrow[kt * 64 + tid];
        __syncthreads();

        // ---- S^T = K Q^T (swapped): regs = 4 consecutive t ----
#pragma unroll
        for (int nt = 0; nt < 4; ++nt) {
            const short8 kf0 = *(const short8*)&Ks[(nt * 16 + lm) * 72 + quad * 8];
            const short8 kf1 = *(const short8*)&Ks[(nt * 16 + lm) * 72 + 32 + quad * 8];
            const int4 amk4 = *(const int4*)&amk_s[nt * 16 + quad * 4];
#pragma unroll
            for (int sub = 0; sub < 2; ++sub) {
                floatx4 s = zz;
                s = __builtin_amdgcn_mfma_f32_16x16x32_bf16(kf0, qf[sub][0], s, 0, 0, 0);
                s = __builtin_amdgcn_mfma_f32_16x16x32_bf16(kf1, qf[sub][1], s, 0, 0, 0);
                const int qg = q0 + sub * 16 + lm;
                const int t0 = kt * 64 + nt * 16 + quad * 4;
                float e0, e1, e2, e3;
                {
                    const bool ok0 = amk4.x && amq[sub] && (t0 + 0 <= qg);
                    const bool ok1 = amk4.y && amq[sub] && (t0 + 1 <= qg);
                    const bool ok2 = amk4.z && amq[sub] && (t0 + 2 <= qg);
                    const bool ok3 = amk4.w && amq[sub] && (t0 + 3 <= qg);
                    e0 = __expf(fminf(ok0 ? s[0] * 0.125f : NEG_BIG, 30.f));
                    e1 = __expf(fminf(ok1 ? s[1] * 0.125f : NEG_BIG, 30.f));
                    e2 = __expf(fminf(ok2 ? s[2] * 0.125f : NEG_BIG, 30.f));
                    e3 = __expf(fminf(ok3 ? s[3] * 0.125f : NEG_BIG, 30.f));
                }
                l_lane[sub] += (e0 + e1) + (e2 + e3);
                ushort4 pv;
                pv.x = f2bf(e0); pv.y = f2bf(e1); pv.z = f2bf(e2); pv.w = f2bf(e3);
                *(ushort4*)&Ps[wq][(sub * 16 + lm) * 72 + nt * 16 + quad * 4] = pv;
            }
        }

        // ---- O^T += V^T P^T (swapped): regs = 4 consecutive hd ----
        short8 af[2][2];
#pragma unroll
        for (int sub = 0; sub < 2; ++sub) {
            af[sub][0] = *(const short8*)&Ps[wq][(sub * 16 + lm) * 72 + quad * 8];
            af[sub][1] = *(const short8*)&Ps[wq][(sub * 16 + lm) * 72 + 32 + quad * 8];
        }
#pragma unroll
        for (int n2 = 0; n2 < 4; ++n2) {
            const short8 vf0 = *(const short8*)&Vts[(n2 * 16 + lm) * 72 + quad * 8];
            const short8 vf1 = *(const short8*)&Vts[(n2 * 16 + lm) * 72 + 32 + quad * 8];
#pragma unroll
            for (int sub = 0; sub < 2; ++sub) {
                o_acc[sub][n2] = __builtin_amdgcn_mfma_f32_16x16x32_bf16(
                    vf0, af[sub][0], o_acc[sub][n2], 0, 0, 0);
                o_acc[sub][n2] = __builtin_amdgcn_mfma_f32_16x16x32_bf16(
                    vf1, af[sub][1], o_acc[sub][n2], 0, 0, 0);
            }
        }
    }

    // ---- l: sum across quads (lane's l covers its t-subset; q = lm) ----
#pragma unroll
    for (int sub = 0; sub < 2; ++sub) {
        float l = l_lane[sub];
        l += __shfl_xor(l, 16);
        l += __shfl_xor(l, 32);
        if (quad == 0)
            lbuf[(size_t)split * (BB * HH * SS) + (size_t)bh * SS + q0 + sub * 16 + lm] = l;
        // ---- epilogue: unnormalized O, packed 4 consecutive hd ----
        const int srow = q0 + sub * 16 + lm;
#pragma unroll
        for (int n2 = 0; n2 < 4; ++n2) {
            ushort4 v;
            v.x = f2bf(o_acc[sub][n2][0]);
            v.y = f2bf(o_acc[sub][n2][1]);
            v.z = f2bf(o_acc[sub][n2][2]);
            v.w = f2bf(o_acc[sub][n2][3]);
            *(ushort4*)(Opart + (size_t)split * (BB * SS * DD)
                        + ((size_t)(b * SS + srow)) * DD + h * HDD + n2 * 16 + quad * 4) = v;
        }
    }
}

// ---------------- combine: A = (O0 + O1) / (l0 + l1), bf16 ----------------
__global__ __launch_bounds__(256) void combine(
    const ushort* __restrict__ Opart, const float* __restrict__ lbuf,
    ushort* __restrict__ Aout)
{
    const size_t e = ((size_t)blockIdx.x * 256 + threadIdx.x) * 8;
    const int m = (int)(e >> 10);
    const int col = (int)(e & 1023);
    const int b = m >> 11, s = m & 2047, h = col >> 6;
    const float l = lbuf[(b * HH + h) * SS + s]
                  + lbuf[BB * HH * SS + (b * HH + h) * SS + s];
    const float inv = l > 0.f ? 1.f / l : 0.f;
    const uint4 u0 = *(const uint4*)(Opart + e);
    const uint4 u1 = *(const uint4*)(Opart + (size_t)BB * SS * DD + e);
    float f0[8], f1[8];
    unpack8(u0, f0);
    unpack8(u1, f1);
    uint4 o;
    o.x = pk2((f0[0] + f1[0]) * inv, (f0[1] + f1[1]) * inv);
    o.y = pk2((f0[2] + f1[2]) * inv, (f0[3] + f1[3]) * inv);
    o.z = pk2((f0[4] + f1[4]) * inv, (f0[5] + f1[5]) * inv);
    o.w = pk2((f0[6] + f1[6]) * inv, (f0[7] + f1[7]) * inv);
    *(uint4*)(Aout + e) = o;
}

extern "C" void kernel_launch(void* const* d_in, const int* in_sizes, int n_in,
                              void* d_out, int out_size, void* d_ws, size_t ws_size,
                              hipStream_t stream) {
    const float* x  = (const float*)d_in[0];
    const int*   am = (const int*)d_in[1];
    const float* Wq = (const float*)d_in[2];
    const float* bq = (const float*)d_in[3];
    const float* Wk = (const float*)d_in[4];
    const float* bk = (const float*)d_in[5];
    const float* Wv = (const float*)d_in[6];
    const float* bv = (const float*)d_in[7];
    const float* Wp = (const float*)d_in[8];
    const float* bp = (const float*)d_in[9];
    float* out = (float*)d_out;

    const size_t elems = (size_t)BB * HH * SS * HDD;  // 4M
    ushort* q_ws = (ushort*)d_ws;                 // Q; later combined A
    ushort* k_ws = q_ws + elems;
    ushort* v_ws = k_ws + elems;                  // V^T (B,H,HD,S)
    float*  lbuf = (float*)(v_ws + elems);        // 2 x 256 KB in a_ws slot

    // d_out scratch: bf16 x (4M) + Wq/Wk/Wv (1M each); later attn partials
    ushort* xb  = (ushort*)d_out;
    ushort* wqb = xb + 4194304;
    ushort* wkb = wqb + 1048576;
    ushort* wvb = wkb + 1048576;

    cvt_all<<<3584, 256, 0, stream>>>(x, Wq, Wk, Wv, xb);

    gemm_mfma<1, ushort, ushort><<<dim3(32, 8, 2), 256, 0, stream>>>(
        xb, wqb, wkb, bq, bk, q_ws, k_ws);
    gemm_mfma<2, ushort, ushort><<<dim3(32, 8, 1), 256, 0, stream>>>(
        xb, wvb, (const ushort*)nullptr, bv, (const float*)nullptr,
        v_ws, (ushort*)nullptr);

    attn_mfma<<<dim3(SS / 128, BB * HH, 2), 256, 0, stream>>>(
        q_ws, k_ws, v_ws, am, (ushort*)d_out, lbuf);

    combine<<<2048, 256, 0, stream>>>((const ushort*)d_out, lbuf, q_ws);

    gemm_mfma<0, float, float><<<dim3(32, 8, 1), 256, 0, stream>>>(
        q_ws, Wp, (const float*)nullptr, bp, (const float*)nullptr,
        out, (float*)nullptr);
}